// Round 1
// baseline (1347.587 us; speedup 1.0000x reference)
//
#include <hip/hip_runtime.h>
#include <hip/hip_bf16.h>
#include <math.h>

// Shapes (compile-time constants from the reference)
constexpr int kB = 8;
constexpr int kT = 16;
constexpr int kN = 1024;
constexpr int kH = 128;
constexpr int kSNP = 4;
constexpr int kNT = kSNP * kN;          // 4096
constexpr int kRows = kB * kNT;         // 32768 GEMM rows
constexpr int kSeqOut = 12;
constexpr float kLRelu = 0.2f;
// Edge layout constants (structure of _build_edges; src VALUES read from input)
constexpr int kEdgePerSnap = kN * 8 + kN;   // 9216
constexpr int kSelfOff = kN * 8;            // 8192
constexpr int kTempBase = kSNP * kEdgePerSnap; // 36864

// ---------------------------------------------------------------------------
// Window build: A[b][t'][n][h] = (t'==0 && !first) ? LN(last) : x[b,tg,n,h]
// x recomputed on the fly from inputs/W_in/b_in/spatial/temporal.
// ---------------------------------------------------------------------------
__global__ void build_fs(const float* __restrict__ inputs, const float* __restrict__ W_in,
                         const float* __restrict__ b_in, const float* __restrict__ spatial,
                         const float* __restrict__ temporal, const float* __restrict__ last,
                         const float* __restrict__ stats, float* __restrict__ A,
                         int left, int first) {
  int idx4 = blockIdx.x * 256 + threadIdx.x;      // over B*4*N*(H/4) = 1,048,576
  int h4 = idx4 & 31;
  int n  = (idx4 >> 5) & 1023;
  int t  = (idx4 >> 15) & 3;
  int b  = idx4 >> 17;
  float4 out;
  if (!first && t == 0) {
    float s1 = stats[b * 2], s2 = stats[b * 2 + 1];
    const float inv = 1.0f / (float)(kN * kH);
    float mu = s1 * inv;
    float var = s2 * inv - mu * mu;
    float sc = rsqrtf(var + 1e-5f);
    float4 v = *(const float4*)(last + ((size_t)(b * kN + n)) * kH + h4 * 4);
    out.x = (v.x - mu) * sc; out.y = (v.y - mu) * sc;
    out.z = (v.z - mu) * sc; out.w = (v.w - mu) * sc;
  } else {
    int tg = left + t - (first ? 0 : 1);
    float2 iv = *(const float2*)(inputs + ((size_t)((b * kT + tg) * kN + n)) * 2);
    float tv = temporal[n * kT + tg];
    float4 w0 = *(const float4*)(W_in + h4 * 4);
    float4 w1 = *(const float4*)(W_in + kH + h4 * 4);
    float4 bb = *(const float4*)(b_in + h4 * 4);
    float4 sp = *(const float4*)(spatial + n * kH + h4 * 4);
    out.x = iv.x * w0.x + iv.y * w1.x + bb.x + sp.x + tv;
    out.y = iv.x * w0.y + iv.y * w1.y + bb.y + sp.y + tv;
    out.z = iv.x * w0.z + iv.y * w1.z + bb.z + sp.z + tv;
    out.w = iv.x * w0.w + iv.y * w1.w + bb.w + sp.w + tv;
  }
  *(float4*)(A + (size_t)idx4 * 4) = out;
}

// ---------------------------------------------------------------------------
// fp32 GEMM: Out[M=32768,128] = In[M,128] @ W[128,128]
// Block: 64 rows x 128 cols, 256 threads, 4x8 micro-tile, K-tiles of 32.
// ---------------------------------------------------------------------------
__launch_bounds__(256)
__global__ void gemm128(const float* __restrict__ In, const float* __restrict__ W,
                        float* __restrict__ Out) {
  __shared__ float As[32][65];     // k-major, padded
  __shared__ float Ws[32][128];
  int tid = threadIdx.x;
  int tx = tid & 15, ty = tid >> 4;
  const float* Ablk = In + (size_t)blockIdx.x * 64 * kH;
  float acc[4][8];
  #pragma unroll
  for (int i = 0; i < 4; ++i)
    #pragma unroll
    for (int j = 0; j < 8; ++j) acc[i][j] = 0.f;

  for (int kt = 0; kt < kH; kt += 32) {
    #pragma unroll
    for (int l = 0; l < 2; ++l) {            // A tile 64x32
      int f = l * 256 + tid;                 // float4 id
      int r = f >> 3, c = f & 7;
      float4 v = *(const float4*)(Ablk + (size_t)r * kH + kt + c * 4);
      int k0 = c * 4;
      As[k0 + 0][r] = v.x; As[k0 + 1][r] = v.y;
      As[k0 + 2][r] = v.z; As[k0 + 3][r] = v.w;
    }
    #pragma unroll
    for (int l = 0; l < 4; ++l) {            // W tile 32x128
      int f = l * 256 + tid;
      int kr = f >> 5, c = f & 31;
      *(float4*)&Ws[kr][c * 4] = *(const float4*)(W + (size_t)(kt + kr) * kH + c * 4);
    }
    __syncthreads();
    #pragma unroll
    for (int kk = 0; kk < 32; ++kk) {
      float4 av = *(const float4*)&As[kk][ty * 4];
      float4 b0 = *(const float4*)&Ws[kk][tx * 4];
      float4 b1 = *(const float4*)&Ws[kk][64 + tx * 4];
      float a[4] = {av.x, av.y, av.z, av.w};
      float bv[8] = {b0.x, b0.y, b0.z, b0.w, b1.x, b1.y, b1.z, b1.w};
      #pragma unroll
      for (int i = 0; i < 4; ++i)
        #pragma unroll
        for (int j = 0; j < 8; ++j) acc[i][j] += a[i] * bv[j];
    }
    __syncthreads();
  }
  int row0 = blockIdx.x * 64 + ty * 4;
  #pragma unroll
  for (int i = 0; i < 4; ++i) {
    float4 o0 = {acc[i][0], acc[i][1], acc[i][2], acc[i][3]};
    float4 o1 = {acc[i][4], acc[i][5], acc[i][6], acc[i][7]};
    *(float4*)(Out + (size_t)(row0 + i) * kH + tx * 4) = o0;
    *(float4*)(Out + (size_t)(row0 + i) * kH + 64 + tx * 4) = o1;
  }
}

// ---------------------------------------------------------------------------
// el/er: per (node, head) 16-dim dots of feat with a_l/a_r
// ---------------------------------------------------------------------------
__global__ void elr_kernel(const float* __restrict__ feat, const float* __restrict__ al,
                           const float* __restrict__ ar, float* __restrict__ el,
                           float* __restrict__ er) {
  int g = blockIdx.x * 256 + threadIdx.x;   // 0 .. 262143
  int h = g & 7;
  int node = g >> 3;
  const float4* f = (const float4*)(feat + (size_t)node * kH + h * 16);
  const float4* L = (const float4*)(al + h * 16);
  const float4* R = (const float4*)(ar + h * 16);
  float sl = 0.f, sr = 0.f;
  #pragma unroll
  for (int j = 0; j < 4; ++j) {
    float4 v = f[j], a = L[j], r = R[j];
    sl += v.x * a.x + v.y * a.y + v.z * a.z + v.w * a.w;
    sr += v.x * r.x + v.y * r.y + v.z * r.z + v.w * r.w;
  }
  el[g] = sl;
  er[g] = sr;
}

// ---------------------------------------------------------------------------
// GAT aggregation. Thread per (b, v, head). <=10 statically-addressed in-edges.
// LAYER 0: out = elu(agg + bias).  LAYER 1: out = agg + bias + residual.
// ---------------------------------------------------------------------------
template <int LAYER>
__global__ void agg_kernel(const float* __restrict__ feat, const float* __restrict__ el,
                           const float* __restrict__ er, const int* __restrict__ esrc,
                           const float* __restrict__ bias, const float* __restrict__ resid,
                           float* __restrict__ outp) {
  int g = blockIdx.x * 256 + threadIdx.x;   // 0 .. 262143
  int h = g & 7;
  int bv = g >> 3;                          // b*4096 + v
  int v = bv & 4095;
  int b = bv >> 12;
  int t = v >> 10;
  int n = v & 1023;

  int srcs[10];
  int base8 = t * kEdgePerSnap + n * 8;
  #pragma unroll
  for (int k = 0; k < 8; ++k) srcs[k] = esrc[base8 + k];
  srcs[8] = esrc[t * kEdgePerSnap + kSelfOff + n];   // self loop (== v)
  float erv = er[bv * 8 + h];
  int ebase = (b << 12) * 8;

  float e[10];
  float m = -1e30f;
  #pragma unroll
  for (int i = 0; i < 9; ++i) {
    float x = el[ebase + srcs[i] * 8 + h] + erv;
    x = x > 0.f ? x : kLRelu * x;
    e[i] = x;
    m = fmaxf(m, x);
  }
  // temporal edge (only for t>0)
  if (t > 0) {
    int s9 = esrc[kTempBase + (t - 1) * kN + n];
    srcs[9] = s9;
    float x = el[ebase + s9 * 8 + h] + erv;
    x = x > 0.f ? x : kLRelu * x;
    e[9] = x;
    m = fmaxf(m, x);
  } else {
    srcs[9] = v;
    e[9] = -1e30f;
  }
  float s = 0.f;
  #pragma unroll
  for (int i = 0; i < 10; ++i) { e[i] = expf(e[i] - m); s += e[i]; }
  float inv = 1.0f / s;

  float4 acc0 = {0,0,0,0}, acc1 = {0,0,0,0}, acc2 = {0,0,0,0}, acc3 = {0,0,0,0};
  size_t fbase = (size_t)(b << 12) * kH;
  #pragma unroll
  for (int i = 0; i < 10; ++i) {
    float w = e[i] * inv;
    const float4* fp = (const float4*)(feat + fbase + (size_t)srcs[i] * kH + h * 16);
    float4 v0 = fp[0], v1 = fp[1], v2 = fp[2], v3 = fp[3];
    acc0.x += w * v0.x; acc0.y += w * v0.y; acc0.z += w * v0.z; acc0.w += w * v0.w;
    acc1.x += w * v1.x; acc1.y += w * v1.y; acc1.z += w * v1.z; acc1.w += w * v1.w;
    acc2.x += w * v2.x; acc2.y += w * v2.y; acc2.z += w * v2.z; acc2.w += w * v2.w;
    acc3.x += w * v3.x; acc3.y += w * v3.y; acc3.z += w * v3.z; acc3.w += w * v3.w;
  }
  size_t ob = (size_t)bv * kH + h * 16;
  const float4* bb = (const float4*)(bias + h * 16);
  float4 accs[4] = {acc0, acc1, acc2, acc3};
  #pragma unroll
  for (int j = 0; j < 4; ++j) {
    float4 a = accs[j], bj = bb[j];
    float4 o;
    if (LAYER == 0) {
      float x0 = a.x + bj.x, x1 = a.y + bj.y, x2 = a.z + bj.z, x3 = a.w + bj.w;
      o.x = x0 > 0.f ? x0 : expm1f(x0);
      o.y = x1 > 0.f ? x1 : expm1f(x1);
      o.z = x2 > 0.f ? x2 : expm1f(x2);
      o.w = x3 > 0.f ? x3 : expm1f(x3);
    } else {
      float4 r = *(const float4*)(resid + ob + j * 4);
      o.x = a.x + bj.x + r.x; o.y = a.y + bj.y + r.y;
      o.z = a.z + bj.z + r.z; o.w = a.w + bj.w + r.w;
    }
    *(float4*)(outp + ob + j * 4) = o;
  }
}

// ---------------------------------------------------------------------------
// Temporal attention pooling + partial LN stats. One wave per (b, n).
// ---------------------------------------------------------------------------
__global__ void attn_kernel(const float* __restrict__ hbuf, const float* __restrict__ q,
                            float* __restrict__ last, float* __restrict__ stats) {
  __shared__ float sred[8];
  int tid = threadIdx.x;
  int wave = tid >> 6, lane = tid & 63;
  int gw = blockIdx.x * 4 + wave;
  int b = gw >> 10, n = gw & 1023;
  int d0 = lane * 2;
  float2 qv = *(const float2*)(q + (size_t)n * kH + d0);
  float2 hv[4];
  float sc[4];
  #pragma unroll
  for (int t = 0; t < 4; ++t) {
    hv[t] = *(const float2*)(hbuf + ((size_t)(b * kNT + t * kN + n)) * kH + d0);
    float p = hv[t].x * qv.x + hv[t].y * qv.y;
    #pragma unroll
    for (int s = 1; s < 64; s <<= 1) p += __shfl_xor(p, s, 64);
    sc[t] = p;
  }
  float m = fmaxf(fmaxf(sc[0], sc[1]), fmaxf(sc[2], sc[3]));
  float a0 = expf(sc[0] - m), a1 = expf(sc[1] - m);
  float a2 = expf(sc[2] - m), a3 = expf(sc[3] - m);
  float id = 1.0f / (a0 + a1 + a2 + a3);
  float lx = (a0 * hv[0].x + a1 * hv[1].x + a2 * hv[2].x + a3 * hv[3].x) * id;
  float ly = (a0 * hv[0].y + a1 * hv[1].y + a2 * hv[2].y + a3 * hv[3].y) * id;
  float2 lo = {lx, ly};
  *(float2*)(last + ((size_t)(b * kN + n)) * kH + d0) = lo;
  float p1 = lx + ly;
  float p2 = lx * lx + ly * ly;
  #pragma unroll
  for (int s = 1; s < 64; s <<= 1) {
    p1 += __shfl_xor(p1, s, 64);
    p2 += __shfl_xor(p2, s, 64);
  }
  if (lane == 0) { sred[wave * 2] = p1; sred[wave * 2 + 1] = p2; }
  __syncthreads();
  if (tid == 0) {
    atomicAdd(&stats[b * 2],     sred[0] + sred[2] + sred[4] + sred[6]);
    atomicAdd(&stats[b * 2 + 1], sred[1] + sred[3] + sred[5] + sred[7]);
  }
}

// ---------------------------------------------------------------------------
// Epilogue: out[b,s,n] = sum_h relu(LN(last)[b,n,h]*w1[s]+b1[s]) * w2[h] + b2
// One wave per (b, n).
// ---------------------------------------------------------------------------
__global__ void out_kernel(const float* __restrict__ last, const float* __restrict__ stats,
                           const float* __restrict__ w1, const float* __restrict__ b1,
                           const float* __restrict__ w2, const float* __restrict__ b2,
                           float* __restrict__ out) {
  int tid = threadIdx.x;
  int wave = tid >> 6, lane = tid & 63;
  int gw = blockIdx.x * 4 + wave;
  int b = gw >> 10, n = gw & 1023;
  float s1 = stats[b * 2], s2 = stats[b * 2 + 1];
  const float inv = 1.0f / (float)(kN * kH);
  float mu = s1 * inv;
  float var = s2 * inv - mu * mu;
  float scv = rsqrtf(var + 1e-5f);
  int d0 = lane * 2;
  float2 lv = *(const float2*)(last + ((size_t)(b * kN + n)) * kH + d0);
  float x0 = (lv.x - mu) * scv, x1 = (lv.y - mu) * scv;
  float w20 = w2[d0], w21 = w2[d0 + 1];
  float bias2 = b2[0];
  #pragma unroll
  for (int s = 0; s < kSeqOut; ++s) {
    float w1s = w1[s], b1s = b1[s];
    float v = fmaxf(x0 * w1s + b1s, 0.f) * w20 + fmaxf(x1 * w1s + b1s, 0.f) * w21;
    #pragma unroll
    for (int k = 1; k < 64; k <<= 1) v += __shfl_xor(v, k, 64);
    if (lane == 0) out[(size_t)(b * kSeqOut + s) * kN + n] = v + bias2;
  }
}

// ---------------------------------------------------------------------------
extern "C" void kernel_launch(void* const* d_in, const int* in_sizes, int n_in,
                              void* d_out, int out_size, void* d_ws, size_t ws_size,
                              hipStream_t stream) {
  const float* inputs   = (const float*)d_in[0];
  const float* W_in     = (const float*)d_in[1];
  const float* b_in     = (const float*)d_in[2];
  const float* spatial  = (const float*)d_in[3];
  const float* temporal = (const float*)d_in[4];
  const float* gw0      = (const float*)d_in[5];
  const float* gal0     = (const float*)d_in[6];
  const float* gar0     = (const float*)d_in[7];
  const float* gb0      = (const float*)d_in[8];
  const float* gw1      = (const float*)d_in[9];
  const float* gal1     = (const float*)d_in[10];
  const float* gar1     = (const float*)d_in[11];
  const float* gb1      = (const float*)d_in[12];
  const float* aggq     = (const float*)d_in[13];
  const float* w_out1   = (const float*)d_in[14];
  const float* b_out1   = (const float*)d_in[15];
  const float* w_out2   = (const float*)d_in[16];
  const float* b_out2   = (const float*)d_in[17];
  const int*   esrc     = (const int*)d_in[18];
  // d_in[19] = edge_dst (layout is static; unused)

  float* ws = (float*)d_ws;
  float* A     = ws;                 // (B,4,N,H)  window / residual   4,194,304
  float* Bf    = ws + 4194304;       // feat buffer                    4,194,304
  float* C     = ws + 8388608;       // layer1 act / h                 4,194,304
  float* el    = ws + 12582912;      // (B*NT, 8)                        262,144
  float* er    = ws + 12845056;      //                                  262,144
  float* last  = ws + 13107200;      // (B,N,H)                        1,048,576
  float* stats = ws + 14155776;      // 5 iters x 8 b x 2                     80

  hipMemsetAsync(stats, 0, 5 * 16 * sizeof(float), stream);

  const int lefts[5] = {0, 4, 7, 10, 13};
  for (int it = 0; it < 5; ++it) {
    const float* st_prev = (it == 0) ? stats : (stats + (it - 1) * 16);
    build_fs<<<4096, 256, 0, stream>>>(inputs, W_in, b_in, spatial, temporal,
                                       last, st_prev, A, lefts[it], it == 0 ? 1 : 0);
    // GAT layer 0
    gemm128<<<kRows / 64, 256, 0, stream>>>(A, gw0, Bf);
    elr_kernel<<<1024, 256, 0, stream>>>(Bf, gal0, gar0, el, er);
    agg_kernel<0><<<1024, 256, 0, stream>>>(Bf, el, er, esrc, gb0, nullptr, C);
    // GAT layer 1
    gemm128<<<kRows / 64, 256, 0, stream>>>(C, gw1, Bf);
    elr_kernel<<<1024, 256, 0, stream>>>(Bf, gal1, gar1, el, er);
    agg_kernel<1><<<1024, 256, 0, stream>>>(Bf, el, er, esrc, gb1, A, C);
    // attention pooling + LN stats
    attn_kernel<<<2048, 256, 0, stream>>>(C, aggq, last, stats + it * 16);
  }
  out_kernel<<<2048, 256, 0, stream>>>(last, stats + 4 * 16, w_out1, b_out1,
                                       w_out2, b_out2, (float*)d_out);
}

// Round 2
// 798.837 us; speedup vs baseline: 1.6869x; 1.6869x over previous
//
#include <hip/hip_runtime.h>
#include <hip/hip_bf16.h>
#include <math.h>

// Shapes (compile-time constants from the reference)
constexpr int kB = 8;
constexpr int kT = 16;
constexpr int kN = 1024;
constexpr int kH = 128;
constexpr int kSNP = 4;
constexpr int kNT = kSNP * kN;          // 4096
constexpr int kRows = kB * kNT;         // 32768 GEMM rows
constexpr int kSeqOut = 12;
constexpr float kLRelu = 0.2f;
// Edge layout constants (structure of _build_edges; src VALUES read from input)
constexpr int kEdgePerSnap = kN * 8 + kN;   // 9216
constexpr int kSelfOff = kN * 8;            // 8192
constexpr int kTempBase = kSNP * kEdgePerSnap; // 36864

// ---------------------------------------------------------------------------
// Window build: A[b][t'][n][h] = (t'==0 && !first) ? LN(last) : x[b,tg,n,h]
// x recomputed on the fly from inputs/W_in/b_in/spatial/temporal.
// XCD-swizzled: batch b -> XCD b (b = blockIdx & 7).
// ---------------------------------------------------------------------------
__global__ void build_fs(const float* __restrict__ inputs, const float* __restrict__ W_in,
                         const float* __restrict__ b_in, const float* __restrict__ spatial,
                         const float* __restrict__ temporal, const float* __restrict__ last,
                         const float* __restrict__ stats, float* __restrict__ A,
                         int left, int first) {
  int blk = blockIdx.x;                 // 4096 blocks; 512 per batch
  int b = blk & 7;
  int inner = blk >> 3;                 // 0..511
  int idx4 = (b << 17) | (inner << 8) | threadIdx.x;  // over B*4*N*(H/4)
  int h4 = idx4 & 31;
  int n  = (idx4 >> 5) & 1023;
  int t  = (idx4 >> 15) & 3;
  float4 out;
  if (!first && t == 0) {
    float s1 = stats[b * 2], s2 = stats[b * 2 + 1];
    const float inv = 1.0f / (float)(kN * kH);
    float mu = s1 * inv;
    float var = s2 * inv - mu * mu;
    float sc = rsqrtf(var + 1e-5f);
    float4 v = *(const float4*)(last + ((size_t)(b * kN + n)) * kH + h4 * 4);
    out.x = (v.x - mu) * sc; out.y = (v.y - mu) * sc;
    out.z = (v.z - mu) * sc; out.w = (v.w - mu) * sc;
  } else {
    int tg = left + t - (first ? 0 : 1);
    float2 iv = *(const float2*)(inputs + ((size_t)((b * kT + tg) * kN + n)) * 2);
    float tv = temporal[n * kT + tg];
    float4 w0 = *(const float4*)(W_in + h4 * 4);
    float4 w1 = *(const float4*)(W_in + kH + h4 * 4);
    float4 bb = *(const float4*)(b_in + h4 * 4);
    float4 sp = *(const float4*)(spatial + n * kH + h4 * 4);
    out.x = iv.x * w0.x + iv.y * w1.x + bb.x + sp.x + tv;
    out.y = iv.x * w0.y + iv.y * w1.y + bb.y + sp.y + tv;
    out.z = iv.x * w0.z + iv.y * w1.z + bb.z + sp.z + tv;
    out.w = iv.x * w0.w + iv.y * w1.w + bb.w + sp.w + tv;
  }
  *(float4*)(A + (size_t)idx4 * 4) = out;
}

// ---------------------------------------------------------------------------
// fp32 GEMM: Out[M=32768,128] = In[M,128] @ W[128,128]
// Block: 64 rows x 128 cols, 256 threads, 4x8 micro-tile, K-tiles of 32.
// XCD-swizzled: batch b (64 row-blocks) -> XCD b.
// ---------------------------------------------------------------------------
__launch_bounds__(256)
__global__ void gemm128(const float* __restrict__ In, const float* __restrict__ W,
                        float* __restrict__ Out) {
  __shared__ float As[32][65];     // k-major, padded
  __shared__ float Ws[32][128];
  int tid = threadIdx.x;
  int tx = tid & 15, ty = tid >> 4;
  int blk = blockIdx.x;            // 512 blocks; 64 per batch
  int rowblk = ((blk & 7) << 6) | (blk >> 3);
  const float* Ablk = In + (size_t)rowblk * 64 * kH;
  float acc[4][8];
  #pragma unroll
  for (int i = 0; i < 4; ++i)
    #pragma unroll
    for (int j = 0; j < 8; ++j) acc[i][j] = 0.f;

  for (int kt = 0; kt < kH; kt += 32) {
    #pragma unroll
    for (int l = 0; l < 2; ++l) {            // A tile 64x32
      int f = l * 256 + tid;                 // float4 id
      int r = f >> 3, c = f & 7;
      float4 v = *(const float4*)(Ablk + (size_t)r * kH + kt + c * 4);
      int k0 = c * 4;
      As[k0 + 0][r] = v.x; As[k0 + 1][r] = v.y;
      As[k0 + 2][r] = v.z; As[k0 + 3][r] = v.w;
    }
    #pragma unroll
    for (int l = 0; l < 4; ++l) {            // W tile 32x128
      int f = l * 256 + tid;
      int kr = f >> 5, c = f & 31;
      *(float4*)&Ws[kr][c * 4] = *(const float4*)(W + (size_t)(kt + kr) * kH + c * 4);
    }
    __syncthreads();
    #pragma unroll
    for (int kk = 0; kk < 32; ++kk) {
      float4 av = *(const float4*)&As[kk][ty * 4];
      float4 b0 = *(const float4*)&Ws[kk][tx * 4];
      float4 b1 = *(const float4*)&Ws[kk][64 + tx * 4];
      float a[4] = {av.x, av.y, av.z, av.w};
      float bv[8] = {b0.x, b0.y, b0.z, b0.w, b1.x, b1.y, b1.z, b1.w};
      #pragma unroll
      for (int i = 0; i < 4; ++i)
        #pragma unroll
        for (int j = 0; j < 8; ++j) acc[i][j] += a[i] * bv[j];
    }
    __syncthreads();
  }
  int row0 = rowblk * 64 + ty * 4;
  #pragma unroll
  for (int i = 0; i < 4; ++i) {
    float4 o0 = {acc[i][0], acc[i][1], acc[i][2], acc[i][3]};
    float4 o1 = {acc[i][4], acc[i][5], acc[i][6], acc[i][7]};
    *(float4*)(Out + (size_t)(row0 + i) * kH + tx * 4) = o0;
    *(float4*)(Out + (size_t)(row0 + i) * kH + 64 + tx * 4) = o1;
  }
}

// ---------------------------------------------------------------------------
// el/er: per (node, head) 16-dim dots of feat with a_l/a_r. XCD-swizzled.
// ---------------------------------------------------------------------------
__global__ void elr_kernel(const float* __restrict__ feat, const float* __restrict__ al,
                           const float* __restrict__ ar, float* __restrict__ el,
                           float* __restrict__ er) {
  int blk = blockIdx.x;                 // 1024 blocks; 128 per batch
  int g = ((blk & 7) << 15) | ((blk >> 3) << 8) | threadIdx.x;  // 0 .. 262143
  int h = g & 7;
  int node = g >> 3;
  const float4* f = (const float4*)(feat + (size_t)node * kH + h * 16);
  const float4* L = (const float4*)(al + h * 16);
  const float4* R = (const float4*)(ar + h * 16);
  float sl = 0.f, sr = 0.f;
  #pragma unroll
  for (int j = 0; j < 4; ++j) {
    float4 v = f[j], a = L[j], r = R[j];
    sl += v.x * a.x + v.y * a.y + v.z * a.z + v.w * a.w;
    sr += v.x * r.x + v.y * r.y + v.z * r.z + v.w * r.w;
  }
  el[g] = sl;
  er[g] = sr;
}

// ---------------------------------------------------------------------------
// GAT aggregation. Thread per (b, v, 8-float slice). <=10 static in-edges.
// 2048 blocks (8/CU); batch b -> XCD b so the gathered feat slice is
// L2-resident on the XCD that just produced it.
// LAYER 0: out = elu(agg + bias).  LAYER 1: out = agg + bias + residual.
// ---------------------------------------------------------------------------
template <int LAYER>
__launch_bounds__(256)
__global__ void agg_kernel(const float* __restrict__ feat, const float* __restrict__ el,
                           const float* __restrict__ er, const int* __restrict__ esrc,
                           const float* __restrict__ bias, const float* __restrict__ resid,
                           float* __restrict__ outp) {
  int blk = blockIdx.x;                 // 2048 blocks; 256 per batch
  int b = blk & 7;
  int inner = blk >> 3;                 // 0..255
  int tid = threadIdx.x;
  int v = inner * 16 + (tid >> 4);      // dst node within snapshot-stack
  int h2 = tid & 15;                    // 8-float slice id (two per head)
  int h = h2 >> 1;
  int t = v >> 10;
  int n = v & 1023;
  int bv = (b << 12) + v;

  int srcs[10];
  int base8 = t * kEdgePerSnap + n * 8;
  #pragma unroll
  for (int k = 0; k < 8; ++k) srcs[k] = esrc[base8 + k];
  srcs[8] = esrc[t * kEdgePerSnap + kSelfOff + n];   // self loop (== v)
  float erv = er[bv * 8 + h];
  int ebase = b << 15;                  // b * 4096 * 8

  float e[10];
  float m = -1e30f;
  #pragma unroll
  for (int i = 0; i < 9; ++i) {
    float x = el[ebase + srcs[i] * 8 + h] + erv;
    x = x > 0.f ? x : kLRelu * x;
    e[i] = x;
    m = fmaxf(m, x);
  }
  // temporal edge (only for t>0)
  if (t > 0) {
    int s9 = esrc[kTempBase + (t - 1) * kN + n];
    srcs[9] = s9;
    float x = el[ebase + s9 * 8 + h] + erv;
    x = x > 0.f ? x : kLRelu * x;
    e[9] = x;
    m = fmaxf(m, x);
  } else {
    srcs[9] = v;
    e[9] = -1e30f;
  }
  float s = 0.f;
  #pragma unroll
  for (int i = 0; i < 10; ++i) { e[i] = expf(e[i] - m); s += e[i]; }
  float inv = 1.0f / s;

  float4 acc0 = {0,0,0,0}, acc1 = {0,0,0,0};
  size_t fbase = (size_t)(b << 12) * kH;
  #pragma unroll
  for (int i = 0; i < 10; ++i) {
    float w = e[i] * inv;
    const float4* fp = (const float4*)(feat + fbase + (size_t)srcs[i] * kH + h2 * 8);
    float4 v0 = fp[0], v1 = fp[1];
    acc0.x += w * v0.x; acc0.y += w * v0.y; acc0.z += w * v0.z; acc0.w += w * v0.w;
    acc1.x += w * v1.x; acc1.y += w * v1.y; acc1.z += w * v1.z; acc1.w += w * v1.w;
  }
  size_t ob = (size_t)bv * kH + h2 * 8;
  const float4* bb = (const float4*)(bias + h2 * 8);
  float4 accs[2] = {acc0, acc1};
  #pragma unroll
  for (int j = 0; j < 2; ++j) {
    float4 a = accs[j], bj = bb[j];
    float4 o;
    if (LAYER == 0) {
      float x0 = a.x + bj.x, x1 = a.y + bj.y, x2 = a.z + bj.z, x3 = a.w + bj.w;
      o.x = x0 > 0.f ? x0 : expm1f(x0);
      o.y = x1 > 0.f ? x1 : expm1f(x1);
      o.z = x2 > 0.f ? x2 : expm1f(x2);
      o.w = x3 > 0.f ? x3 : expm1f(x3);
    } else {
      float4 r = *(const float4*)(resid + ob + j * 4);
      o.x = a.x + bj.x + r.x; o.y = a.y + bj.y + r.y;
      o.z = a.z + bj.z + r.z; o.w = a.w + bj.w + r.w;
    }
    *(float4*)(outp + ob + j * 4) = o;
  }
}

// ---------------------------------------------------------------------------
// Temporal attention pooling + partial LN stats. One wave per (b, n).
// XCD-swizzled: batch b -> XCD b.
// ---------------------------------------------------------------------------
__global__ void attn_kernel(const float* __restrict__ hbuf, const float* __restrict__ q,
                            float* __restrict__ last, float* __restrict__ stats) {
  __shared__ float sred[8];
  int tid = threadIdx.x;
  int wave = tid >> 6, lane = tid & 63;
  int blk = blockIdx.x;                 // 2048 blocks; 256 per batch
  int b = blk & 7;
  int gw = (b << 10) | ((blk >> 3) * 4 + wave);
  int n = gw & 1023;
  int d0 = lane * 2;
  float2 qv = *(const float2*)(q + (size_t)n * kH + d0);
  float2 hv[4];
  float sc[4];
  #pragma unroll
  for (int t = 0; t < 4; ++t) {
    hv[t] = *(const float2*)(hbuf + ((size_t)(b * kNT + t * kN + n)) * kH + d0);
    float p = hv[t].x * qv.x + hv[t].y * qv.y;
    #pragma unroll
    for (int s = 1; s < 64; s <<= 1) p += __shfl_xor(p, s, 64);
    sc[t] = p;
  }
  float m = fmaxf(fmaxf(sc[0], sc[1]), fmaxf(sc[2], sc[3]));
  float a0 = expf(sc[0] - m), a1 = expf(sc[1] - m);
  float a2 = expf(sc[2] - m), a3 = expf(sc[3] - m);
  float id = 1.0f / (a0 + a1 + a2 + a3);
  float lx = (a0 * hv[0].x + a1 * hv[1].x + a2 * hv[2].x + a3 * hv[3].x) * id;
  float ly = (a0 * hv[0].y + a1 * hv[1].y + a2 * hv[2].y + a3 * hv[3].y) * id;
  float2 lo = {lx, ly};
  *(float2*)(last + ((size_t)(b * kN + n)) * kH + d0) = lo;
  float p1 = lx + ly;
  float p2 = lx * lx + ly * ly;
  #pragma unroll
  for (int s = 1; s < 64; s <<= 1) {
    p1 += __shfl_xor(p1, s, 64);
    p2 += __shfl_xor(p2, s, 64);
  }
  if (lane == 0) { sred[wave * 2] = p1; sred[wave * 2 + 1] = p2; }
  __syncthreads();
  if (tid == 0) {
    atomicAdd(&stats[b * 2],     sred[0] + sred[2] + sred[4] + sred[6]);
    atomicAdd(&stats[b * 2 + 1], sred[1] + sred[3] + sred[5] + sred[7]);
  }
}

// ---------------------------------------------------------------------------
// Epilogue: out[b,s,n] = sum_h relu(LN(last)[b,n,h]*w1[s]+b1[s]) * w2[h] + b2
// One wave per (b, n).
// ---------------------------------------------------------------------------
__global__ void out_kernel(const float* __restrict__ last, const float* __restrict__ stats,
                           const float* __restrict__ w1, const float* __restrict__ b1,
                           const float* __restrict__ w2, const float* __restrict__ b2,
                           float* __restrict__ out) {
  int tid = threadIdx.x;
  int wave = tid >> 6, lane = tid & 63;
  int gw = blockIdx.x * 4 + wave;
  int b = gw >> 10, n = gw & 1023;
  float s1 = stats[b * 2], s2 = stats[b * 2 + 1];
  const float inv = 1.0f / (float)(kN * kH);
  float mu = s1 * inv;
  float var = s2 * inv - mu * mu;
  float scv = rsqrtf(var + 1e-5f);
  int d0 = lane * 2;
  float2 lv = *(const float2*)(last + ((size_t)(b * kN + n)) * kH + d0);
  float x0 = (lv.x - mu) * scv, x1 = (lv.y - mu) * scv;
  float w20 = w2[d0], w21 = w2[d0 + 1];
  float bias2 = b2[0];
  #pragma unroll
  for (int s = 0; s < kSeqOut; ++s) {
    float w1s = w1[s], b1s = b1[s];
    float v = fmaxf(x0 * w1s + b1s, 0.f) * w20 + fmaxf(x1 * w1s + b1s, 0.f) * w21;
    #pragma unroll
    for (int k = 1; k < 64; k <<= 1) v += __shfl_xor(v, k, 64);
    if (lane == 0) out[(size_t)(b * kSeqOut + s) * kN + n] = v + bias2;
  }
}

// ---------------------------------------------------------------------------
extern "C" void kernel_launch(void* const* d_in, const int* in_sizes, int n_in,
                              void* d_out, int out_size, void* d_ws, size_t ws_size,
                              hipStream_t stream) {
  const float* inputs   = (const float*)d_in[0];
  const float* W_in     = (const float*)d_in[1];
  const float* b_in     = (const float*)d_in[2];
  const float* spatial  = (const float*)d_in[3];
  const float* temporal = (const float*)d_in[4];
  const float* gw0      = (const float*)d_in[5];
  const float* gal0     = (const float*)d_in[6];
  const float* gar0     = (const float*)d_in[7];
  const float* gb0      = (const float*)d_in[8];
  const float* gw1      = (const float*)d_in[9];
  const float* gal1     = (const float*)d_in[10];
  const float* gar1     = (const float*)d_in[11];
  const float* gb1      = (const float*)d_in[12];
  const float* aggq     = (const float*)d_in[13];
  const float* w_out1   = (const float*)d_in[14];
  const float* b_out1   = (const float*)d_in[15];
  const float* w_out2   = (const float*)d_in[16];
  const float* b_out2   = (const float*)d_in[17];
  const int*   esrc     = (const int*)d_in[18];
  // d_in[19] = edge_dst (layout is static; unused)

  float* ws = (float*)d_ws;
  float* A     = ws;                 // (B,4,N,H)  window / residual   4,194,304
  float* Bf    = ws + 4194304;       // feat buffer                    4,194,304
  float* C     = ws + 8388608;       // layer1 act / h                 4,194,304
  float* el    = ws + 12582912;      // (B*NT, 8)                        262,144
  float* er    = ws + 12845056;      //                                  262,144
  float* last  = ws + 13107200;      // (B,N,H)                        1,048,576
  float* stats = ws + 14155776;      // 5 iters x 8 b x 2                     80

  hipMemsetAsync(stats, 0, 5 * 16 * sizeof(float), stream);

  const int lefts[5] = {0, 4, 7, 10, 13};
  for (int it = 0; it < 5; ++it) {
    const float* st_prev = (it == 0) ? stats : (stats + (it - 1) * 16);
    build_fs<<<4096, 256, 0, stream>>>(inputs, W_in, b_in, spatial, temporal,
                                       last, st_prev, A, lefts[it], it == 0 ? 1 : 0);
    // GAT layer 0
    gemm128<<<kRows / 64, 256, 0, stream>>>(A, gw0, Bf);
    elr_kernel<<<1024, 256, 0, stream>>>(Bf, gal0, gar0, el, er);
    agg_kernel<0><<<2048, 256, 0, stream>>>(Bf, el, er, esrc, gb0, nullptr, C);
    // GAT layer 1
    gemm128<<<kRows / 64, 256, 0, stream>>>(C, gw1, Bf);
    elr_kernel<<<1024, 256, 0, stream>>>(Bf, gal1, gar1, el, er);
    agg_kernel<1><<<2048, 256, 0, stream>>>(Bf, el, er, esrc, gb1, A, C);
    // attention pooling + LN stats
    attn_kernel<<<2048, 256, 0, stream>>>(C, aggq, last, stats + it * 16);
  }
  out_kernel<<<2048, 256, 0, stream>>>(last, stats + 4 * 16, w_out1, b_out1,
                                       w_out2, b_out2, (float*)d_out);
}

// Round 3
// 566.378 us; speedup vs baseline: 2.3793x; 1.4104x over previous
//
#include <hip/hip_runtime.h>
#include <hip/hip_bf16.h>
#include <math.h>

// Shapes (compile-time constants from the reference)
constexpr int kB = 8;
constexpr int kT = 16;
constexpr int kN = 1024;
constexpr int kH = 128;
constexpr int kSNP = 4;
constexpr int kNT = kSNP * kN;          // 4096
constexpr int kRows = kB * kNT;         // 32768 GEMM rows
constexpr int kSeqOut = 12;
constexpr float kLRelu = 0.2f;
// Edge layout constants (structure of _build_edges; src VALUES read from input)
constexpr int kEdgePerSnap = kN * 8 + kN;   // 9216
constexpr int kSelfOff = kN * 8;            // 8192
constexpr int kTempBase = kSNP * kEdgePerSnap; // 36864
// stats layout: [iter][b][slot][16] floats -> per-(b,slot) 64-B line
constexpr int kStatsPerIter = kB * 8 * 16;  // 1024 floats

// ---------------------------------------------------------------------------
// Window build: A[b][t'][n][h] = (t'==0 && !first) ? LN(last) : x[b,tg,n,h]
// x recomputed on the fly from inputs/W_in/b_in/spatial/temporal.
// XCD-swizzled: batch b -> XCD b (b = blockIdx & 7).
// ---------------------------------------------------------------------------
__global__ void build_fs(const float* __restrict__ inputs, const float* __restrict__ W_in,
                         const float* __restrict__ b_in, const float* __restrict__ spatial,
                         const float* __restrict__ temporal, const float* __restrict__ last,
                         const float* __restrict__ stats, float* __restrict__ A,
                         int left, int first) {
  int blk = blockIdx.x;                 // 4096 blocks; 512 per batch
  int b = blk & 7;
  int inner = blk >> 3;                 // 0..511
  int idx4 = (b << 17) | (inner << 8) | threadIdx.x;  // over B*4*N*(H/4)
  int h4 = idx4 & 31;
  int n  = (idx4 >> 5) & 1023;
  int t  = (idx4 >> 15) & 3;
  float4 out;
  if (!first && t == 0) {
    float s1 = 0.f, s2 = 0.f;
    #pragma unroll
    for (int s = 0; s < 8; ++s) {
      s1 += stats[b * 128 + s * 16];
      s2 += stats[b * 128 + s * 16 + 1];
    }
    const float inv = 1.0f / (float)(kN * kH);
    float mu = s1 * inv;
    float var = s2 * inv - mu * mu;
    float sc = rsqrtf(var + 1e-5f);
    float4 v = *(const float4*)(last + ((size_t)(b * kN + n)) * kH + h4 * 4);
    out.x = (v.x - mu) * sc; out.y = (v.y - mu) * sc;
    out.z = (v.z - mu) * sc; out.w = (v.w - mu) * sc;
  } else {
    int tg = left + t - (first ? 0 : 1);
    float2 iv = *(const float2*)(inputs + ((size_t)((b * kT + tg) * kN + n)) * 2);
    float tv = temporal[n * kT + tg];
    float4 w0 = *(const float4*)(W_in + h4 * 4);
    float4 w1 = *(const float4*)(W_in + kH + h4 * 4);
    float4 bb = *(const float4*)(b_in + h4 * 4);
    float4 sp = *(const float4*)(spatial + n * kH + h4 * 4);
    out.x = iv.x * w0.x + iv.y * w1.x + bb.x + sp.x + tv;
    out.y = iv.x * w0.y + iv.y * w1.y + bb.y + sp.y + tv;
    out.z = iv.x * w0.z + iv.y * w1.z + bb.z + sp.z + tv;
    out.w = iv.x * w0.w + iv.y * w1.w + bb.w + sp.w + tv;
  }
  *(float4*)(A + (size_t)idx4 * 4) = out;
}

// ---------------------------------------------------------------------------
// fp32 GEMM: Out[M=32768,128] = In[M,128] @ W[128,128]
// Block: 64 rows x 128 cols, 256 threads, 4x8 micro-tile, K-tiles of 32.
// XCD-swizzled: batch b (64 row-blocks) -> XCD b.
// ---------------------------------------------------------------------------
__launch_bounds__(256)
__global__ void gemm128(const float* __restrict__ In, const float* __restrict__ W,
                        float* __restrict__ Out) {
  __shared__ float As[32][65];     // k-major, padded
  __shared__ float Ws[32][128];
  int tid = threadIdx.x;
  int tx = tid & 15, ty = tid >> 4;
  int blk = blockIdx.x;            // 512 blocks; 64 per batch
  int rowblk = ((blk & 7) << 6) | (blk >> 3);
  const float* Ablk = In + (size_t)rowblk * 64 * kH;
  float acc[4][8];
  #pragma unroll
  for (int i = 0; i < 4; ++i)
    #pragma unroll
    for (int j = 0; j < 8; ++j) acc[i][j] = 0.f;

  for (int kt = 0; kt < kH; kt += 32) {
    #pragma unroll
    for (int l = 0; l < 2; ++l) {            // A tile 64x32
      int f = l * 256 + tid;                 // float4 id
      int r = f >> 3, c = f & 7;
      float4 v = *(const float4*)(Ablk + (size_t)r * kH + kt + c * 4);
      int k0 = c * 4;
      As[k0 + 0][r] = v.x; As[k0 + 1][r] = v.y;
      As[k0 + 2][r] = v.z; As[k0 + 3][r] = v.w;
    }
    #pragma unroll
    for (int l = 0; l < 4; ++l) {            // W tile 32x128
      int f = l * 256 + tid;
      int kr = f >> 5, c = f & 31;
      *(float4*)&Ws[kr][c * 4] = *(const float4*)(W + (size_t)(kt + kr) * kH + c * 4);
    }
    __syncthreads();
    #pragma unroll
    for (int kk = 0; kk < 32; ++kk) {
      float4 av = *(const float4*)&As[kk][ty * 4];
      float4 b0 = *(const float4*)&Ws[kk][tx * 4];
      float4 b1 = *(const float4*)&Ws[kk][64 + tx * 4];
      float a[4] = {av.x, av.y, av.z, av.w};
      float bv[8] = {b0.x, b0.y, b0.z, b0.w, b1.x, b1.y, b1.z, b1.w};
      #pragma unroll
      for (int i = 0; i < 4; ++i)
        #pragma unroll
        for (int j = 0; j < 8; ++j) acc[i][j] += a[i] * bv[j];
    }
    __syncthreads();
  }
  int row0 = rowblk * 64 + ty * 4;
  #pragma unroll
  for (int i = 0; i < 4; ++i) {
    float4 o0 = {acc[i][0], acc[i][1], acc[i][2], acc[i][3]};
    float4 o1 = {acc[i][4], acc[i][5], acc[i][6], acc[i][7]};
    *(float4*)(Out + (size_t)(row0 + i) * kH + tx * 4) = o0;
    *(float4*)(Out + (size_t)(row0 + i) * kH + 64 + tx * 4) = o1;
  }
}

// ---------------------------------------------------------------------------
// el/er: per (node, head) 16-dim dots of feat with a_l/a_r. XCD-swizzled.
// ---------------------------------------------------------------------------
__global__ void elr_kernel(const float* __restrict__ feat, const float* __restrict__ al,
                           const float* __restrict__ ar, float* __restrict__ el,
                           float* __restrict__ er) {
  int blk = blockIdx.x;                 // 1024 blocks; 128 per batch
  int g = ((blk & 7) << 15) | ((blk >> 3) << 8) | threadIdx.x;  // 0 .. 262143
  int h = g & 7;
  int node = g >> 3;
  const float4* f = (const float4*)(feat + (size_t)node * kH + h * 16);
  const float4* L = (const float4*)(al + h * 16);
  const float4* R = (const float4*)(ar + h * 16);
  float sl = 0.f, sr = 0.f;
  #pragma unroll
  for (int j = 0; j < 4; ++j) {
    float4 v = f[j], a = L[j], r = R[j];
    sl += v.x * a.x + v.y * a.y + v.z * a.z + v.w * a.w;
    sr += v.x * r.x + v.y * r.y + v.z * r.z + v.w * r.w;
  }
  el[g] = sl;
  er[g] = sr;
}

// ---------------------------------------------------------------------------
// GAT aggregation. Thread per (b, v, 8-float slice). <=10 static in-edges.
// 2048 blocks (8/CU); batch b -> XCD b so the gathered feat slice is
// L2-resident on the XCD that just produced it.
// LAYER 0: out = elu(agg + bias).  LAYER 1: out = agg + bias + residual.
// ---------------------------------------------------------------------------
template <int LAYER>
__launch_bounds__(256)
__global__ void agg_kernel(const float* __restrict__ feat, const float* __restrict__ el,
                           const float* __restrict__ er, const int* __restrict__ esrc,
                           const float* __restrict__ bias, const float* __restrict__ resid,
                           float* __restrict__ outp) {
  int blk = blockIdx.x;                 // 2048 blocks; 256 per batch
  int b = blk & 7;
  int inner = blk >> 3;                 // 0..255
  int tid = threadIdx.x;
  int v = inner * 16 + (tid >> 4);      // dst node within snapshot-stack
  int h2 = tid & 15;                    // 8-float slice id (two per head)
  int h = h2 >> 1;
  int t = v >> 10;
  int n = v & 1023;
  int bv = (b << 12) + v;

  int srcs[10];
  int base8 = t * kEdgePerSnap + n * 8;
  #pragma unroll
  for (int k = 0; k < 8; ++k) srcs[k] = esrc[base8 + k];
  srcs[8] = esrc[t * kEdgePerSnap + kSelfOff + n];   // self loop (== v)
  float erv = er[bv * 8 + h];
  int ebase = b << 15;                  // b * 4096 * 8

  float e[10];
  float m = -1e30f;
  #pragma unroll
  for (int i = 0; i < 9; ++i) {
    float x = el[ebase + srcs[i] * 8 + h] + erv;
    x = x > 0.f ? x : kLRelu * x;
    e[i] = x;
    m = fmaxf(m, x);
  }
  // temporal edge (only for t>0)
  if (t > 0) {
    int s9 = esrc[kTempBase + (t - 1) * kN + n];
    srcs[9] = s9;
    float x = el[ebase + s9 * 8 + h] + erv;
    x = x > 0.f ? x : kLRelu * x;
    e[9] = x;
    m = fmaxf(m, x);
  } else {
    srcs[9] = v;
    e[9] = -1e30f;
  }
  float s = 0.f;
  #pragma unroll
  for (int i = 0; i < 10; ++i) { e[i] = expf(e[i] - m); s += e[i]; }
  float inv = 1.0f / s;

  float4 acc0 = {0,0,0,0}, acc1 = {0,0,0,0};
  size_t fbase = (size_t)(b << 12) * kH;
  #pragma unroll
  for (int i = 0; i < 10; ++i) {
    float w = e[i] * inv;
    const float4* fp = (const float4*)(feat + fbase + (size_t)srcs[i] * kH + h2 * 8);
    float4 v0 = fp[0], v1 = fp[1];
    acc0.x += w * v0.x; acc0.y += w * v0.y; acc0.z += w * v0.z; acc0.w += w * v0.w;
    acc1.x += w * v1.x; acc1.y += w * v1.y; acc1.z += w * v1.z; acc1.w += w * v1.w;
  }
  size_t ob = (size_t)bv * kH + h2 * 8;
  const float4* bb = (const float4*)(bias + h2 * 8);
  float4 accs[2] = {acc0, acc1};
  #pragma unroll
  for (int j = 0; j < 2; ++j) {
    float4 a = accs[j], bj = bb[j];
    float4 o;
    if (LAYER == 0) {
      float x0 = a.x + bj.x, x1 = a.y + bj.y, x2 = a.z + bj.z, x3 = a.w + bj.w;
      o.x = x0 > 0.f ? x0 : expm1f(x0);
      o.y = x1 > 0.f ? x1 : expm1f(x1);
      o.z = x2 > 0.f ? x2 : expm1f(x2);
      o.w = x3 > 0.f ? x3 : expm1f(x3);
    } else {
      float4 r = *(const float4*)(resid + ob + j * 4);
      o.x = a.x + bj.x + r.x; o.y = a.y + bj.y + r.y;
      o.z = a.z + bj.z + r.z; o.w = a.w + bj.w + r.w;
    }
    *(float4*)(outp + ob + j * 4) = o;
  }
}

// ---------------------------------------------------------------------------
// Temporal attention pooling + partial LN stats. One wave per (b, n) x4.
// 512 blocks (2/CU); batch b -> XCD b. Each wave handles 4 n values and
// accumulates LN partials in registers; ONE atomic pair per block into a
// per-(b,slot) padded 64-B line (8 slots/batch) to avoid line contention.
// ---------------------------------------------------------------------------
__global__ void attn_kernel(const float* __restrict__ hbuf, const float* __restrict__ q,
                            float* __restrict__ last, float* __restrict__ stats) {
  __shared__ float sred[8];
  int tid = threadIdx.x;
  int wave = tid >> 6, lane = tid & 63;
  int blk = blockIdx.x;                 // 512 blocks; 64 per batch
  int b = blk & 7;
  int inner = blk >> 3;                 // 0..63
  int d0 = lane * 2;
  float p1 = 0.f, p2 = 0.f;
  for (int i = 0; i < 4; ++i) {
    int n = inner * 16 + wave * 4 + i;
    float2 qv = *(const float2*)(q + (size_t)n * kH + d0);
    float2 hv[4];
    float sc[4];
    #pragma unroll
    for (int t = 0; t < 4; ++t) {
      hv[t] = *(const float2*)(hbuf + ((size_t)(b * kNT + t * kN + n)) * kH + d0);
      float p = hv[t].x * qv.x + hv[t].y * qv.y;
      #pragma unroll
      for (int s = 1; s < 64; s <<= 1) p += __shfl_xor(p, s, 64);
      sc[t] = p;
    }
    float m = fmaxf(fmaxf(sc[0], sc[1]), fmaxf(sc[2], sc[3]));
    float a0 = expf(sc[0] - m), a1 = expf(sc[1] - m);
    float a2 = expf(sc[2] - m), a3 = expf(sc[3] - m);
    float id = 1.0f / (a0 + a1 + a2 + a3);
    float lx = (a0 * hv[0].x + a1 * hv[1].x + a2 * hv[2].x + a3 * hv[3].x) * id;
    float ly = (a0 * hv[0].y + a1 * hv[1].y + a2 * hv[2].y + a3 * hv[3].y) * id;
    float2 lo = {lx, ly};
    *(float2*)(last + ((size_t)(b * kN + n)) * kH + d0) = lo;
    p1 += lx + ly;
    p2 += lx * lx + ly * ly;
  }
  #pragma unroll
  for (int s = 1; s < 64; s <<= 1) {
    p1 += __shfl_xor(p1, s, 64);
    p2 += __shfl_xor(p2, s, 64);
  }
  if (lane == 0) { sred[wave * 2] = p1; sred[wave * 2 + 1] = p2; }
  __syncthreads();
  if (tid == 0) {
    int slot = inner & 7;
    atomicAdd(&stats[b * 128 + slot * 16],     sred[0] + sred[2] + sred[4] + sred[6]);
    atomicAdd(&stats[b * 128 + slot * 16 + 1], sred[1] + sred[3] + sred[5] + sred[7]);
  }
}

// ---------------------------------------------------------------------------
// Epilogue: out[b,s,n] = sum_h relu(LN(last)[b,n,h]*w1[s]+b1[s]) * w2[h] + b2
// One wave per (b, n).
// ---------------------------------------------------------------------------
__global__ void out_kernel(const float* __restrict__ last, const float* __restrict__ stats,
                           const float* __restrict__ w1, const float* __restrict__ b1,
                           const float* __restrict__ w2, const float* __restrict__ b2,
                           float* __restrict__ out) {
  int tid = threadIdx.x;
  int wave = tid >> 6, lane = tid & 63;
  int gw = blockIdx.x * 4 + wave;
  int b = gw >> 10, n = gw & 1023;
  float s1 = 0.f, s2 = 0.f;
  #pragma unroll
  for (int s = 0; s < 8; ++s) {
    s1 += stats[b * 128 + s * 16];
    s2 += stats[b * 128 + s * 16 + 1];
  }
  const float inv = 1.0f / (float)(kN * kH);
  float mu = s1 * inv;
  float var = s2 * inv - mu * mu;
  float scv = rsqrtf(var + 1e-5f);
  int d0 = lane * 2;
  float2 lv = *(const float2*)(last + ((size_t)(b * kN + n)) * kH + d0);
  float x0 = (lv.x - mu) * scv, x1 = (lv.y - mu) * scv;
  float w20 = w2[d0], w21 = w2[d0 + 1];
  float bias2 = b2[0];
  #pragma unroll
  for (int s = 0; s < kSeqOut; ++s) {
    float w1s = w1[s], b1s = b1[s];
    float v = fmaxf(x0 * w1s + b1s, 0.f) * w20 + fmaxf(x1 * w1s + b1s, 0.f) * w21;
    #pragma unroll
    for (int k = 1; k < 64; k <<= 1) v += __shfl_xor(v, k, 64);
    if (lane == 0) out[(size_t)(b * kSeqOut + s) * kN + n] = v + bias2;
  }
}

// ---------------------------------------------------------------------------
extern "C" void kernel_launch(void* const* d_in, const int* in_sizes, int n_in,
                              void* d_out, int out_size, void* d_ws, size_t ws_size,
                              hipStream_t stream) {
  const float* inputs   = (const float*)d_in[0];
  const float* W_in     = (const float*)d_in[1];
  const float* b_in     = (const float*)d_in[2];
  const float* spatial  = (const float*)d_in[3];
  const float* temporal = (const float*)d_in[4];
  const float* gw0      = (const float*)d_in[5];
  const float* gal0     = (const float*)d_in[6];
  const float* gar0     = (const float*)d_in[7];
  const float* gb0      = (const float*)d_in[8];
  const float* gw1      = (const float*)d_in[9];
  const float* gal1     = (const float*)d_in[10];
  const float* gar1     = (const float*)d_in[11];
  const float* gb1      = (const float*)d_in[12];
  const float* aggq     = (const float*)d_in[13];
  const float* w_out1   = (const float*)d_in[14];
  const float* b_out1   = (const float*)d_in[15];
  const float* w_out2   = (const float*)d_in[16];
  const float* b_out2   = (const float*)d_in[17];
  const int*   esrc     = (const int*)d_in[18];
  // d_in[19] = edge_dst (layout is static; unused)

  float* ws = (float*)d_ws;
  float* A     = ws;                 // (B,4,N,H)  window / residual   4,194,304
  float* Bf    = ws + 4194304;       // feat buffer                    4,194,304
  float* C     = ws + 8388608;       // layer1 act / h                 4,194,304
  float* el    = ws + 12582912;      // (B*NT, 8)                        262,144
  float* er    = ws + 12845056;      //                                  262,144
  float* last  = ws + 13107200;      // (B,N,H)                        1,048,576
  float* stats = ws + 14155776;      // 5 iters x [8 b][8 slot][16]        5120

  hipMemsetAsync(stats, 0, 5 * kStatsPerIter * sizeof(float), stream);

  const int lefts[5] = {0, 4, 7, 10, 13};
  for (int it = 0; it < 5; ++it) {
    const float* st_prev = (it == 0) ? stats : (stats + (it - 1) * kStatsPerIter);
    build_fs<<<4096, 256, 0, stream>>>(inputs, W_in, b_in, spatial, temporal,
                                       last, st_prev, A, lefts[it], it == 0 ? 1 : 0);
    // GAT layer 0
    gemm128<<<kRows / 64, 256, 0, stream>>>(A, gw0, Bf);
    elr_kernel<<<1024, 256, 0, stream>>>(Bf, gal0, gar0, el, er);
    agg_kernel<0><<<2048, 256, 0, stream>>>(Bf, el, er, esrc, gb0, nullptr, C);
    // GAT layer 1
    gemm128<<<kRows / 64, 256, 0, stream>>>(C, gw1, Bf);
    elr_kernel<<<1024, 256, 0, stream>>>(Bf, gal1, gar1, el, er);
    agg_kernel<1><<<2048, 256, 0, stream>>>(Bf, el, er, esrc, gb1, A, C);
    // attention pooling + LN stats
    attn_kernel<<<512, 256, 0, stream>>>(C, aggq, last, stats + it * kStatsPerIter);
  }
  out_kernel<<<2048, 256, 0, stream>>>(last, stats + 4 * kStatsPerIter, w_out1, b_out1,
                                       w_out2, b_out2, (float*)d_out);
}

// Round 4
// 487.254 us; speedup vs baseline: 2.7657x; 1.1624x over previous
//
#include <hip/hip_runtime.h>
#include <hip/hip_bf16.h>
#include <math.h>

// Shapes (compile-time constants from the reference)
constexpr int kB = 8;
constexpr int kT = 16;
constexpr int kN = 1024;
constexpr int kH = 128;
constexpr int kSNP = 4;
constexpr int kNT = kSNP * kN;          // 4096
constexpr int kRows = kB * kNT;         // 32768 GEMM rows
constexpr int kSeqOut = 12;
constexpr float kLRelu = 0.2f;
// Edge layout constants (structure of _build_edges; src VALUES read from input)
constexpr int kEdgePerSnap = kN * 8 + kN;   // 9216
constexpr int kSelfOff = kN * 8;            // 8192
constexpr int kTempBase = kSNP * kEdgePerSnap; // 36864
// stats layout: [iter][b][slot][16] floats -> per-(b,slot) 64-B line
constexpr int kStatsPerIter = kB * 8 * 16;  // 1024 floats

typedef __bf16 bf16x8 __attribute__((ext_vector_type(8)));
typedef float f32x4 __attribute__((ext_vector_type(4)));

// ---------------------------------------------------------------------------
// Window build: A[b][t'][n][h] = (t'==0 && !first) ? LN(last) : x[b,tg,n,h]
// x recomputed on the fly from inputs/W_in/b_in/spatial/temporal.
// XCD-swizzled: batch b -> XCD b (b = blockIdx & 7).
// ---------------------------------------------------------------------------
__global__ void build_fs(const float* __restrict__ inputs, const float* __restrict__ W_in,
                         const float* __restrict__ b_in, const float* __restrict__ spatial,
                         const float* __restrict__ temporal, const float* __restrict__ last,
                         const float* __restrict__ stats, float* __restrict__ A,
                         int left, int first) {
  int blk = blockIdx.x;                 // 4096 blocks; 512 per batch
  int b = blk & 7;
  int inner = blk >> 3;                 // 0..511
  int idx4 = (b << 17) | (inner << 8) | threadIdx.x;  // over B*4*N*(H/4)
  int h4 = idx4 & 31;
  int n  = (idx4 >> 5) & 1023;
  int t  = (idx4 >> 15) & 3;
  float4 out;
  if (!first && t == 0) {
    float s1 = 0.f, s2 = 0.f;
    #pragma unroll
    for (int s = 0; s < 8; ++s) {
      s1 += stats[b * 128 + s * 16];
      s2 += stats[b * 128 + s * 16 + 1];
    }
    const float inv = 1.0f / (float)(kN * kH);
    float mu = s1 * inv;
    float var = s2 * inv - mu * mu;
    float sc = rsqrtf(var + 1e-5f);
    float4 v = *(const float4*)(last + ((size_t)(b * kN + n)) * kH + h4 * 4);
    out.x = (v.x - mu) * sc; out.y = (v.y - mu) * sc;
    out.z = (v.z - mu) * sc; out.w = (v.w - mu) * sc;
  } else {
    int tg = left + t - (first ? 0 : 1);
    float2 iv = *(const float2*)(inputs + ((size_t)((b * kT + tg) * kN + n)) * 2);
    float tv = temporal[n * kT + tg];
    float4 w0 = *(const float4*)(W_in + h4 * 4);
    float4 w1 = *(const float4*)(W_in + kH + h4 * 4);
    float4 bb = *(const float4*)(b_in + h4 * 4);
    float4 sp = *(const float4*)(spatial + n * kH + h4 * 4);
    out.x = iv.x * w0.x + iv.y * w1.x + bb.x + sp.x + tv;
    out.y = iv.x * w0.y + iv.y * w1.y + bb.y + sp.y + tv;
    out.z = iv.x * w0.z + iv.y * w1.z + bb.z + sp.z + tv;
    out.w = iv.x * w0.w + iv.y * w1.w + bb.w + sp.w + tv;
  }
  *(float4*)(A + (size_t)idx4 * 4) = out;
}

// ---------------------------------------------------------------------------
// Split-bf16 MFMA GEMM + fused el/er epilogue.
// Out[M,128] = In[M,128] @ W[128,128]  (fp32-accurate via Ah@Wh+Al@Wh+Ah@Wl)
// Block: 64 rows x 128 cols, 4 waves, each wave 64 rows x 32 cols (2 heads).
// A tile staged in LDS as bf16 hi/lo, XOR-swizzled (byte ^= (row&7)<<4).
// W fragments live in registers (converted fp32->bf16 hi/lo per block).
// Epilogue computes el/er = sum_d feat*a_{l,r} via 16-lane shfl butterflies.
// XCD-swizzled: batch b (64 row-blocks of 64) -> XCD b.
// ---------------------------------------------------------------------------
__launch_bounds__(256)
__global__ void gemm_mfma(const float* __restrict__ In, const float* __restrict__ W,
                          const float* __restrict__ gal, const float* __restrict__ gar,
                          float* __restrict__ Out, float* __restrict__ elp,
                          float* __restrict__ erp) {
  __shared__ unsigned short AhL[64 * 128];   // 16 KB, swizzled bf16 hi
  __shared__ unsigned short AlL[64 * 128];   // 16 KB, swizzled bf16 lo
  int tid = threadIdx.x;
  int lane = tid & 63, wid = tid >> 6;
  int blk = blockIdx.x;            // 512 blocks; 64 per batch
  int rowblk = ((blk & 7) << 6) | (blk >> 3);
  int blockRow0 = rowblk * 64;

  // ---- W fragments into registers (hi/lo bf16) ----
  union BU { unsigned short u[8]; bf16x8 v; };
  BU bh[2][4], bl[2][4];
  int colL = lane & 15;
  int kgrp = (lane >> 4) * 8;
  #pragma unroll
  for (int c = 0; c < 2; ++c) {
    int col = wid * 32 + c * 16 + colL;
    #pragma unroll
    for (int s = 0; s < 4; ++s) {
      #pragma unroll
      for (int j = 0; j < 8; ++j) {
        int k = s * 32 + kgrp + j;
        float w = W[k * kH + col];
        unsigned int bits = __float_as_uint(w);
        bh[c][s].u[j] = (unsigned short)(bits >> 16);
        float hif = __uint_as_float(bits & 0xffff0000u);
        bl[c][s].u[j] = (unsigned short)(__float_as_uint(w - hif) >> 16);
      }
    }
  }

  // ---- Stage A tile (64x128 fp32) -> LDS bf16 hi/lo, swizzled ----
  const float* Ablk = In + (size_t)blockRow0 * kH;
  #pragma unroll
  for (int itn = 0; itn < 8; ++itn) {
    int fid = itn * 256 + tid;
    int row = fid >> 5, kq = fid & 31;     // 32 float4 per row
    float4 v = *(const float4*)(Ablk + (size_t)row * kH + kq * 4);
    ushort4 hi, lo;
    unsigned int bx = __float_as_uint(v.x);
    hi.x = bx >> 16; lo.x = __float_as_uint(v.x - __uint_as_float(bx & 0xffff0000u)) >> 16;
    unsigned int by = __float_as_uint(v.y);
    hi.y = by >> 16; lo.y = __float_as_uint(v.y - __uint_as_float(by & 0xffff0000u)) >> 16;
    unsigned int bz = __float_as_uint(v.z);
    hi.z = bz >> 16; lo.z = __float_as_uint(v.z - __uint_as_float(bz & 0xffff0000u)) >> 16;
    unsigned int bw = __float_as_uint(v.w);
    hi.w = bw >> 16; lo.w = __float_as_uint(v.w - __uint_as_float(bw & 0xffff0000u)) >> 16;
    int boff = (row * 256 + kq * 8) ^ ((row & 7) << 4);
    *(ushort4*)((char*)AhL + boff) = hi;
    *(ushort4*)((char*)AlL + boff) = lo;
  }
  __syncthreads();

  // ---- MFMA main loop: K = 4 steps of 32 ----
  f32x4 acc[4][2];
  #pragma unroll
  for (int rb = 0; rb < 4; ++rb)
    #pragma unroll
    for (int c = 0; c < 2; ++c) acc[rb][c] = (f32x4){0.f, 0.f, 0.f, 0.f};

  #pragma unroll
  for (int s = 0; s < 4; ++s) {
    bf16x8 ah[4], alr[4];
    #pragma unroll
    for (int rb = 0; rb < 4; ++rb) {
      int row = rb * 16 + colL;
      int boff = (row * 256 + s * 64 + (lane >> 4) * 16) ^ ((row & 7) << 4);
      ah[rb]  = *(const bf16x8*)((const char*)AhL + boff);
      alr[rb] = *(const bf16x8*)((const char*)AlL + boff);
    }
    #pragma unroll
    for (int c = 0; c < 2; ++c) {
      #pragma unroll
      for (int rb = 0; rb < 4; ++rb)
        acc[rb][c] = __builtin_amdgcn_mfma_f32_16x16x32_bf16(ah[rb], bh[c][s].v, acc[rb][c], 0, 0, 0);
      #pragma unroll
      for (int rb = 0; rb < 4; ++rb)
        acc[rb][c] = __builtin_amdgcn_mfma_f32_16x16x32_bf16(alr[rb], bh[c][s].v, acc[rb][c], 0, 0, 0);
      #pragma unroll
      for (int rb = 0; rb < 4; ++rb)
        acc[rb][c] = __builtin_amdgcn_mfma_f32_16x16x32_bf16(ah[rb], bl[c][s].v, acc[rb][c], 0, 0, 0);
    }
  }

  // ---- Epilogue: store feat + fused el/er ----
  int rquad = (lane >> 4) * 4;
  #pragma unroll
  for (int c = 0; c < 2; ++c) {
    int h = wid * 2 + c;
    float alv = gal[h * 16 + colL];
    float arv = gar[h * 16 + colL];
    int col = wid * 32 + c * 16 + colL;
    #pragma unroll
    for (int rb = 0; rb < 4; ++rb) {
      f32x4 a = acc[rb][c];
      int row0g = blockRow0 + rb * 16 + rquad;
      #pragma unroll
      for (int r = 0; r < 4; ++r)
        Out[(size_t)(row0g + r) * kH + col] = a[r];
      float e0 = a[0] * alv, e1 = a[1] * alv, e2 = a[2] * alv, e3 = a[3] * alv;
      float f0 = a[0] * arv, f1 = a[1] * arv, f2 = a[2] * arv, f3 = a[3] * arv;
      #pragma unroll
      for (int m = 1; m < 16; m <<= 1) {
        e0 += __shfl_xor(e0, m, 64); e1 += __shfl_xor(e1, m, 64);
        e2 += __shfl_xor(e2, m, 64); e3 += __shfl_xor(e3, m, 64);
        f0 += __shfl_xor(f0, m, 64); f1 += __shfl_xor(f1, m, 64);
        f2 += __shfl_xor(f2, m, 64); f3 += __shfl_xor(f3, m, 64);
      }
      if (colL == 0) {
        elp[(size_t)(row0g + 0) * 8 + h] = e0;
        elp[(size_t)(row0g + 1) * 8 + h] = e1;
        elp[(size_t)(row0g + 2) * 8 + h] = e2;
        elp[(size_t)(row0g + 3) * 8 + h] = e3;
        erp[(size_t)(row0g + 0) * 8 + h] = f0;
        erp[(size_t)(row0g + 1) * 8 + h] = f1;
        erp[(size_t)(row0g + 2) * 8 + h] = f2;
        erp[(size_t)(row0g + 3) * 8 + h] = f3;
      }
    }
  }
}

// ---------------------------------------------------------------------------
// GAT aggregation. Thread per (b, v, 8-float slice). <=10 static in-edges.
// 2048 blocks (8/CU); batch b -> XCD b so the gathered feat slice is
// L2-resident on the XCD that just produced it.
// LAYER 0: out = elu(agg + bias).  LAYER 1: out = agg + bias + residual.
// ---------------------------------------------------------------------------
template <int LAYER>
__launch_bounds__(256)
__global__ void agg_kernel(const float* __restrict__ feat, const float* __restrict__ el,
                           const float* __restrict__ er, const int* __restrict__ esrc,
                           const float* __restrict__ bias, const float* __restrict__ resid,
                           float* __restrict__ outp) {
  int blk = blockIdx.x;                 // 2048 blocks; 256 per batch
  int b = blk & 7;
  int inner = blk >> 3;                 // 0..255
  int tid = threadIdx.x;
  int v = inner * 16 + (tid >> 4);      // dst node within snapshot-stack
  int h2 = tid & 15;                    // 8-float slice id (two per head)
  int h = h2 >> 1;
  int t = v >> 10;
  int n = v & 1023;
  int bv = (b << 12) + v;

  int srcs[10];
  int base8 = t * kEdgePerSnap + n * 8;
  #pragma unroll
  for (int k = 0; k < 8; ++k) srcs[k] = esrc[base8 + k];
  srcs[8] = esrc[t * kEdgePerSnap + kSelfOff + n];   // self loop (== v)
  float erv = er[bv * 8 + h];
  int ebase = b << 15;                  // b * 4096 * 8

  float e[10];
  float m = -1e30f;
  #pragma unroll
  for (int i = 0; i < 9; ++i) {
    float x = el[ebase + srcs[i] * 8 + h] + erv;
    x = x > 0.f ? x : kLRelu * x;
    e[i] = x;
    m = fmaxf(m, x);
  }
  // temporal edge (only for t>0)
  if (t > 0) {
    int s9 = esrc[kTempBase + (t - 1) * kN + n];
    srcs[9] = s9;
    float x = el[ebase + s9 * 8 + h] + erv;
    x = x > 0.f ? x : kLRelu * x;
    e[9] = x;
    m = fmaxf(m, x);
  } else {
    srcs[9] = v;
    e[9] = -1e30f;
  }
  float s = 0.f;
  #pragma unroll
  for (int i = 0; i < 10; ++i) { e[i] = expf(e[i] - m); s += e[i]; }
  float inv = 1.0f / s;

  float4 acc0 = {0,0,0,0}, acc1 = {0,0,0,0};
  size_t fbase = (size_t)(b << 12) * kH;
  #pragma unroll
  for (int i = 0; i < 10; ++i) {
    float w = e[i] * inv;
    const float4* fp = (const float4*)(feat + fbase + (size_t)srcs[i] * kH + h2 * 8);
    float4 v0 = fp[0], v1 = fp[1];
    acc0.x += w * v0.x; acc0.y += w * v0.y; acc0.z += w * v0.z; acc0.w += w * v0.w;
    acc1.x += w * v1.x; acc1.y += w * v1.y; acc1.z += w * v1.z; acc1.w += w * v1.w;
  }
  size_t ob = (size_t)bv * kH + h2 * 8;
  const float4* bb = (const float4*)(bias + h2 * 8);
  float4 accs[2] = {acc0, acc1};
  #pragma unroll
  for (int j = 0; j < 2; ++j) {
    float4 a = accs[j], bj = bb[j];
    float4 o;
    if (LAYER == 0) {
      float x0 = a.x + bj.x, x1 = a.y + bj.y, x2 = a.z + bj.z, x3 = a.w + bj.w;
      o.x = x0 > 0.f ? x0 : expm1f(x0);
      o.y = x1 > 0.f ? x1 : expm1f(x1);
      o.z = x2 > 0.f ? x2 : expm1f(x2);
      o.w = x3 > 0.f ? x3 : expm1f(x3);
    } else {
      float4 r = *(const float4*)(resid + ob + j * 4);
      o.x = a.x + bj.x + r.x; o.y = a.y + bj.y + r.y;
      o.z = a.z + bj.z + r.z; o.w = a.w + bj.w + r.w;
    }
    *(float4*)(outp + ob + j * 4) = o;
  }
}

// ---------------------------------------------------------------------------
// Temporal attention pooling + partial LN stats. One wave per (b, n) x4.
// 512 blocks (2/CU); batch b -> XCD b. Each wave handles 4 n values and
// accumulates LN partials in registers; ONE atomic pair per block into a
// per-(b,slot) padded 64-B line (8 slots/batch) to avoid line contention.
// ---------------------------------------------------------------------------
__global__ void attn_kernel(const float* __restrict__ hbuf, const float* __restrict__ q,
                            float* __restrict__ last, float* __restrict__ stats) {
  __shared__ float sred[8];
  int tid = threadIdx.x;
  int wave = tid >> 6, lane = tid & 63;
  int blk = blockIdx.x;                 // 512 blocks; 64 per batch
  int b = blk & 7;
  int inner = blk >> 3;                 // 0..63
  int d0 = lane * 2;
  float p1 = 0.f, p2 = 0.f;
  for (int i = 0; i < 4; ++i) {
    int n = inner * 16 + wave * 4 + i;
    float2 qv = *(const float2*)(q + (size_t)n * kH + d0);
    float2 hv[4];
    float sc[4];
    #pragma unroll
    for (int t = 0; t < 4; ++t) {
      hv[t] = *(const float2*)(hbuf + ((size_t)(b * kNT + t * kN + n)) * kH + d0);
      float p = hv[t].x * qv.x + hv[t].y * qv.y;
      #pragma unroll
      for (int s = 1; s < 64; s <<= 1) p += __shfl_xor(p, s, 64);
      sc[t] = p;
    }
    float m = fmaxf(fmaxf(sc[0], sc[1]), fmaxf(sc[2], sc[3]));
    float a0 = expf(sc[0] - m), a1 = expf(sc[1] - m);
    float a2 = expf(sc[2] - m), a3 = expf(sc[3] - m);
    float id = 1.0f / (a0 + a1 + a2 + a3);
    float lx = (a0 * hv[0].x + a1 * hv[1].x + a2 * hv[2].x + a3 * hv[3].x) * id;
    float ly = (a0 * hv[0].y + a1 * hv[1].y + a2 * hv[2].y + a3 * hv[3].y) * id;
    float2 lo = {lx, ly};
    *(float2*)(last + ((size_t)(b * kN + n)) * kH + d0) = lo;
    p1 += lx + ly;
    p2 += lx * lx + ly * ly;
  }
  #pragma unroll
  for (int s = 1; s < 64; s <<= 1) {
    p1 += __shfl_xor(p1, s, 64);
    p2 += __shfl_xor(p2, s, 64);
  }
  if (lane == 0) { sred[wave * 2] = p1; sred[wave * 2 + 1] = p2; }
  __syncthreads();
  if (tid == 0) {
    int slot = inner & 7;
    atomicAdd(&stats[b * 128 + slot * 16],     sred[0] + sred[2] + sred[4] + sred[6]);
    atomicAdd(&stats[b * 128 + slot * 16 + 1], sred[1] + sred[3] + sred[5] + sred[7]);
  }
}

// ---------------------------------------------------------------------------
// Epilogue: out[b,s,n] = sum_h relu(LN(last)[b,n,h]*w1[s]+b1[s]) * w2[h] + b2
// One wave per (b, n).
// ---------------------------------------------------------------------------
__global__ void out_kernel(const float* __restrict__ last, const float* __restrict__ stats,
                           const float* __restrict__ w1, const float* __restrict__ b1,
                           const float* __restrict__ w2, const float* __restrict__ b2,
                           float* __restrict__ out) {
  int tid = threadIdx.x;
  int wave = tid >> 6, lane = tid & 63;
  int gw = blockIdx.x * 4 + wave;
  int b = gw >> 10, n = gw & 1023;
  float s1 = 0.f, s2 = 0.f;
  #pragma unroll
  for (int s = 0; s < 8; ++s) {
    s1 += stats[b * 128 + s * 16];
    s2 += stats[b * 128 + s * 16 + 1];
  }
  const float inv = 1.0f / (float)(kN * kH);
  float mu = s1 * inv;
  float var = s2 * inv - mu * mu;
  float scv = rsqrtf(var + 1e-5f);
  int d0 = lane * 2;
  float2 lv = *(const float2*)(last + ((size_t)(b * kN + n)) * kH + d0);
  float x0 = (lv.x - mu) * scv, x1 = (lv.y - mu) * scv;
  float w20 = w2[d0], w21 = w2[d0 + 1];
  float bias2 = b2[0];
  #pragma unroll
  for (int s = 0; s < kSeqOut; ++s) {
    float w1s = w1[s], b1s = b1[s];
    float v = fmaxf(x0 * w1s + b1s, 0.f) * w20 + fmaxf(x1 * w1s + b1s, 0.f) * w21;
    #pragma unroll
    for (int k = 1; k < 64; k <<= 1) v += __shfl_xor(v, k, 64);
    if (lane == 0) out[(size_t)(b * kSeqOut + s) * kN + n] = v + bias2;
  }
}

// ---------------------------------------------------------------------------
extern "C" void kernel_launch(void* const* d_in, const int* in_sizes, int n_in,
                              void* d_out, int out_size, void* d_ws, size_t ws_size,
                              hipStream_t stream) {
  const float* inputs   = (const float*)d_in[0];
  const float* W_in     = (const float*)d_in[1];
  const float* b_in     = (const float*)d_in[2];
  const float* spatial  = (const float*)d_in[3];
  const float* temporal = (const float*)d_in[4];
  const float* gw0      = (const float*)d_in[5];
  const float* gal0     = (const float*)d_in[6];
  const float* gar0     = (const float*)d_in[7];
  const float* gb0      = (const float*)d_in[8];
  const float* gw1      = (const float*)d_in[9];
  const float* gal1     = (const float*)d_in[10];
  const float* gar1     = (const float*)d_in[11];
  const float* gb1      = (const float*)d_in[12];
  const float* aggq     = (const float*)d_in[13];
  const float* w_out1   = (const float*)d_in[14];
  const float* b_out1   = (const float*)d_in[15];
  const float* w_out2   = (const float*)d_in[16];
  const float* b_out2   = (const float*)d_in[17];
  const int*   esrc     = (const int*)d_in[18];
  // d_in[19] = edge_dst (layout is static; unused)

  float* ws = (float*)d_ws;
  float* A     = ws;                 // (B,4,N,H)  window / residual   4,194,304
  float* Bf    = ws + 4194304;       // feat buffer                    4,194,304
  float* C     = ws + 8388608;       // layer1 act / h                 4,194,304
  float* el    = ws + 12582912;      // (B*NT, 8)                        262,144
  float* er    = ws + 12845056;      //                                  262,144
  float* last  = ws + 13107200;      // (B,N,H)                        1,048,576
  float* stats = ws + 14155776;      // 5 iters x [8 b][8 slot][16]        5120

  hipMemsetAsync(stats, 0, 5 * kStatsPerIter * sizeof(float), stream);

  const int lefts[5] = {0, 4, 7, 10, 13};
  for (int it = 0; it < 5; ++it) {
    const float* st_prev = (it == 0) ? stats : (stats + (it - 1) * kStatsPerIter);
    build_fs<<<4096, 256, 0, stream>>>(inputs, W_in, b_in, spatial, temporal,
                                       last, st_prev, A, lefts[it], it == 0 ? 1 : 0);
    // GAT layer 0 (GEMM + fused el/er)
    gemm_mfma<<<kRows / 64, 256, 0, stream>>>(A, gw0, gal0, gar0, Bf, el, er);
    agg_kernel<0><<<2048, 256, 0, stream>>>(Bf, el, er, esrc, gb0, nullptr, C);
    // GAT layer 1
    gemm_mfma<<<kRows / 64, 256, 0, stream>>>(C, gw1, gal1, gar1, Bf, el, er);
    agg_kernel<1><<<2048, 256, 0, stream>>>(Bf, el, er, esrc, gb1, A, C);
    // attention pooling + LN stats
    attn_kernel<<<512, 256, 0, stream>>>(C, aggq, last, stats + it * kStatsPerIter);
  }
  out_kernel<<<2048, 256, 0, stream>>>(last, stats + 4 * kStatsPerIter, w_out1, b_out1,
                                       w_out2, b_out2, (float*)d_out);
}